// Round 4
// baseline (89.455 us; speedup 1.0000x reference)
//
#include <hip/hip_runtime.h>

// Problem constants (fixed by setup_inputs in the reference)
constexpr int B = 8, C = 64, H = 64, W = 64;
constexpr int N = 512;          // rois per leading dim
constexpr int R = N * B;        // 4096 total ROIs
constexpr int HW = H * W;

// Antiderivative of tent kernel max(0, 1-|t|), clipped to [-1, 1].
__device__ __forceinline__ float tent_int(float t) {
    t = fminf(1.0f, fmaxf(-1.0f, t));
    float u = t + 1.0f;
    float v = 1.0f - t;
    return (t < 0.0f) ? 0.5f * u * u : 1.0f - 0.5f * v * v;
}

// ---------------------------------------------------------------------------
// R14 == R13 resubmitted verbatim: the R3 bench died with "MI355X container
// failed twice" (broker/infra failure, no kernel result). Keeping the source
// identical so the measurement cleanly tests the R13 hypothesis.
//
// R13: SINGLE-DISPATCH direct kernel. One block (128 thr) per ROI, reading
// the fp32 [B,C,H,W] feature directly — no transpose kernel, no bf16
// workspace, no second dispatch. History:
//   * R11 cooperative fusion: grid.sync across 8 non-coherent XCDs cost
//     ~100us. Never re-fuse with grid-wide sync.
//   * R12 (2-wave split) gained only 1.4us -> main kernel was already ~3-5us;
//     the timed path is dominated by the 44us workspace re-poison fill +
//     ~15us fixed dispatch/replay overhead. So: cut dispatches 2->1 and
//     stop touching d_ws entirely (tests whether the fill is conditional).
// Thread map: cgrp = t>>4 (8 channel planes {cgrp, 8+cgrp, ...}),
// j16 = t&15 (one window column). Per row: 8 independent loads (wave =
// 4-8 contiguous 64B segments, L2/LLC-served; feature is 8.4MB) + 8 FMA.
// Column weight wxl=0 kills padded/OOB columns; addresses clamped in-bounds.
// Reduce: 4x shfl_xor over j-bits (within-wave), 256B LDS transpose,
// coalesced 256B store. fp32 end-to-end (absmax should drop vs bf16 path).
// ---------------------------------------------------------------------------
__global__ __launch_bounds__(128) void prroi_direct(
    const float* __restrict__ feature,   // [B, C, H, W] fp32
    const float* __restrict__ rois,      // [N, B, 1, 1, 5]
    float* __restrict__ out)             // [R, C]
{
    const int r    = blockIdx.x;
    const int t    = threadIdx.x;
    const int cgrp = t >> 4;             // 0..7
    const int j16  = t & 15;             // column within padded window

    const int bo = r >> 9;               // r / N (N=512)
    const int n  = r & 511;
    const float* rp = rois + ((size_t)n * B + bo) * 5;

    const int   b  = (int)rp[0];
    const float x1 = rp[1], y1 = rp[2], x2 = rp[3], y2 = rp[4];

    const int i_lo = max(0, (int)ceilf(y1 - 1.0f));
    const int i_hi = min(H - 1, (int)floorf(y2 + 1.0f));
    const int j_lo = max(0, (int)ceilf(x1 - 1.0f));
    const int j_hi = min(W - 1, (int)floorf(x2 + 1.0f));
    const int ny = i_hi - i_lo + 1;      // 5..15
    const int nx = j_hi - j_lo + 1;      // 5..15

    // This thread's column weight (0 outside the true window) + clamped col.
    const int   j   = j_lo + j16;
    const float jf  = (float)j;
    const float wxl = (j16 < nx) ? (tent_int(x2 - jf) - tent_int(x1 - jf)) : 0.0f;
    const int   jcl = min(j, W - 1);

    // Base pointer at (channel cgrp, row i_lo, col jcl); channel plane
    // stride 8*HW floats between the 8 accumulating channels.
    const float* p0 = feature + ((size_t)b * C + cgrp) * HW
                              + (size_t)i_lo * W + jcl;

    float acc[8] = {0.f, 0.f, 0.f, 0.f, 0.f, 0.f, 0.f, 0.f};
    for (int ii = 0; ii < ny; ++ii) {
        const float fi = (float)(i_lo + ii);
        const float wy = tent_int(y2 - fi) - tent_int(y1 - fi);  // wave-uniform
        const float w  = wy * wxl;
        const float* prow = p0 + (size_t)ii * W;
        float v[8];
        #pragma unroll
        for (int co = 0; co < 8; ++co)          // 8 independent loads (MLP=8)
            v[co] = prow[(size_t)co * 8 * HW];
        #pragma unroll
        for (int co = 0; co < 8; ++co)
            acc[co] = fmaf(w, v[co], acc[co]);
    }

    // Reduce over the 16 window columns (lane bits 0..3, within-wave).
    #pragma unroll
    for (int co = 0; co < 8; ++co) {
        acc[co] += __shfl_xor(acc[co], 1);
        acc[co] += __shfl_xor(acc[co], 2);
        acc[co] += __shfl_xor(acc[co], 4);
        acc[co] += __shfl_xor(acc[co], 8);
    }

    // mean over 49 bins of integ/bin_area == acc / ((x2-x1)(y2-y1))
    const float prod  = (x2 - x1) * (y2 - y1);
    const float scale = (prod > 0.0f) ? (1.0f / fmaxf(prod, 49e-12f)) : 0.0f;

    // Gather the 64 channel sums (8 holder threads x 8 channels, stride 8)
    // through 256B of LDS, then one coalesced 256B store from wave 0.
    __shared__ float obuf[64];
    if (j16 == 0) {
        #pragma unroll
        for (int co = 0; co < 8; ++co)
            obuf[co * 8 + cgrp] = acc[co] * scale;
    }
    __syncthreads();
    if (t < 64) out[(size_t)r * C + t] = obuf[t];
}

extern "C" void kernel_launch(void* const* d_in, const int* in_sizes, int n_in,
                              void* d_out, int out_size, void* d_ws, size_t ws_size,
                              hipStream_t stream) {
    const float* feature = (const float*)d_in[0];
    const float* rois    = (const float*)d_in[1];
    float* out           = (float*)d_out;
    (void)d_ws; (void)ws_size;           // deliberately unused (see R13 note)

    prroi_direct<<<R, 128, 0, stream>>>(feature, rois, out);
}

// Round 5
// 69.390 us; speedup vs baseline: 1.2892x; 1.2892x over previous
//
#include <hip/hip_runtime.h>

// Problem constants (fixed by setup_inputs in the reference)
constexpr int B = 8, C = 64, H = 64, W = 64;
constexpr int N = 512;          // rois per leading dim
constexpr int R = N * B;        // 4096 total ROIs
constexpr int HW = H * W;

// Antiderivative of tent kernel max(0, 1-|t|), clipped to [-1, 1].
__device__ __forceinline__ float tent_int(float t) {
    t = fminf(1.0f, fmaxf(-1.0f, t));
    float u = t + 1.0f;
    float v = 1.0f - t;
    return (t < 0.0f) ? 0.5f * u * u : 1.0f - 0.5f * v * v;
}

__device__ __forceinline__ float bf_lo(unsigned int u) {    // low short -> f32
    union { unsigned int i; float f; } c; c.i = u << 16; return c.f;
}
__device__ __forceinline__ float bf_hi(unsigned int u) {    // high short -> f32
    union { unsigned int i; float f; } c; c.i = u & 0xFFFF0000u; return c.f;
}
__device__ __forceinline__ unsigned short f2bf(float x) {   // round-to-nearest-even
    union { float f; unsigned int i; } c; c.f = x;
    unsigned int r = c.i + 0x7FFFu + ((c.i >> 16) & 1u);
    return (unsigned short)(r >> 16);
}

// ---------------------------------------------------------------------------
// Session ledger (do not re-learn these):
//   * R11: cooperative grid.sync across 8 XCDs cost ~100us. Never re-fuse.
//   * R13/R14: direct fp32 [C,H,W] gather (no transpose) = ~30us kernel,
//     ~4x slower than transpose+bf16 path: scattered unaligned 64B segments
//     waste half of each cache line and double the bytes. Transpose stays.
//   * The 268MB/~42us fillBufferAligned re-poison runs UNCONDITIONALLY
//     (R14 touched no workspace; fill still there). Timed-path floor =
//     fill ~42 + replay residue ~18; our kernels are only ~8us of 69.9.
//
// Kernel 1 (R15): transpose [B,C,HW] f32 -> [B,HW,C] bf16, leaner than R9:
// 1024 blocks x 256 thr, 32-px strips. float4 global loads (8x128B
// segments/wave-instr), LDS tile [px][ch] pad-68, float2 LDS reads
// (2-way bank conflicts only = free), packed 2xbf16 uint stores
// (256B contiguous/wave-instr). Half the per-value instruction count of R9.
// ---------------------------------------------------------------------------
__global__ __launch_bounds__(256) void transpose_kernel(
    const float* __restrict__ in,          // [B, C, HW] fp32
    unsigned short* __restrict__ out)      // [B, HW, C] bf16
{
    __shared__ float tile[32][68];           // [px][ch], pad 68 (8.5 KB)
    const int b  = blockIdx.x >> 7;          // 0..7
    const int tp = (blockIdx.x & 127) * 32;  // pixel strip start
    const int t  = threadIdx.x;

    // Load: thread covers ch = (t>>3) + {0,32}, 4 px at colq = 4*(t&7).
    const int c0   = t >> 3;                 // 0..31
    const int colq = (t & 7) * 4;            // 0,4,...,28
    const float* src = in + (size_t)b * C * HW + tp + colq;
    #pragma unroll
    for (int s = 0; s < 2; ++s) {
        const int ch = c0 + s * 32;
        const float4 v = *reinterpret_cast<const float4*>(src + (size_t)ch * HW);
        tile[colq + 0][ch] = v.x;
        tile[colq + 1][ch] = v.y;
        tile[colq + 2][ch] = v.z;
        tile[colq + 3][ch] = v.w;
    }
    __syncthreads();

    // Store: lane packs channels {2lc, 2lc+1} of one pixel into a uint;
    // each wave-instr covers 2 pixels = 256B contiguous.
    const int w    = t >> 6;                 // wave 0..3
    const int l    = t & 63;
    const int half = l >> 5;                 // 0,1
    const int lc   = l & 31;                 // channel-pair index
    unsigned int* dst = reinterpret_cast<unsigned int*>(
        out + ((size_t)b * HW + tp) * C);
    #pragma unroll
    for (int k = 0; k < 4; ++k) {
        const int p = k * 8 + w * 2 + half;  // 0..31
        const float2 v = *reinterpret_cast<const float2*>(&tile[p][lc * 2]);
        dst[(size_t)p * 32 + lc] = (unsigned int)f2bf(v.x)
                                 | ((unsigned int)f2bf(v.y) << 16);
    }
}

// ---------------------------------------------------------------------------
// Kernel 2: main PrRoIPool, TWO WAVES PER ROI (even/odd rows). R12 version
// VERBATIM — proven 69.9us config; do not touch.
// ---------------------------------------------------------------------------
__global__ __launch_bounds__(128) void prroi_main2(
    const unsigned short* __restrict__ ft, // [B, HW, C] bf16
    const float* __restrict__ rois,        // [N, B, 1, 1, 5]
    float* __restrict__ out)               // [R, C]
{
    const int r    = blockIdx.x;
    const int t    = threadIdx.x;
    const int wid  = t >> 6;             // 0,1 : row-parity wave
    const int lane = t & 63;
    const int pg   = lane >> 3;          // pixel subgroup 0..7
    const int cg_  = lane & 7;           // channel group (8 channels)

    const int bo = r >> 9;               // r / N (N=512)
    const int n  = r & 511;
    const float* rp = rois + ((size_t)n * B + bo) * 5;

    const int   b  = (int)rp[0];
    const float x1 = rp[1], y1 = rp[2], x2 = rp[3], y2 = rp[4];

    const int i_lo = max(0, (int)ceilf(y1 - 1.0f));
    const int i_hi = min(H - 1, (int)floorf(y2 + 1.0f));
    const int j_lo = max(0, (int)ceilf(x1 - 1.0f));
    const int j_hi = min(W - 1, (int)floorf(x2 + 1.0f));
    const int ny = i_hi - i_lo + 1;      // 5..15
    const int nx = j_hi - j_lo + 1;      // 5..15

    // Per-lane column weight + element offset (clamped addr, 0 weight OOB).
    float wx[2];
    int   coff[2];
    #pragma unroll
    for (int k = 0; k < 2; ++k) {
        const int  jj    = k * 8 + pg;
        const int  j     = j_lo + jj;
        const bool valid = (jj < nx);
        const float jf   = (float)j;
        wx[k]   = valid ? (tent_int(x2 - jf) - tent_int(x1 - jf)) : 0.0f;
        coff[k] = min(j, W - 1) * C + cg_ * 8;     // element (short) offset
    }

    float acc[8] = {0.f, 0.f, 0.f, 0.f, 0.f, 0.f, 0.f, 0.f};
    const unsigned short* fb = ft + ((size_t)b * HW + (size_t)i_lo * W) * C;

    // Preload this wave's first row (clamped; ny >= 5 so wid < ny always).
    uint4 c0, c1;
    {
        const unsigned short* rowp = fb + (size_t)min(wid, ny - 1) * (W * C);
        c0 = *reinterpret_cast<const uint4*>(rowp + coff[0]);
        c1 = *reinterpret_cast<const uint4*>(rowp + coff[1]);
    }
    for (int ii = wid; ii < ny; ii += 2) {
        // Prefetch next row for this wave (clamped -> always a valid load;
        // garbage only on the final iteration where it is never consumed).
        const unsigned short* rown = fb + (size_t)min(ii + 2, ny - 1) * (W * C);
        const uint4 n0 = *reinterpret_cast<const uint4*>(rown + coff[0]);
        const uint4 n1 = *reinterpret_cast<const uint4*>(rown + coff[1]);

        const float fi = (float)(i_lo + ii);
        const float wy = tent_int(y2 - fi) - tent_int(y1 - fi);  // wave-uniform
        const float w0 = wy * wx[0];
        const float w1 = wy * wx[1];
        acc[0] = fmaf(w0, bf_lo(c0.x), acc[0]);
        acc[1] = fmaf(w0, bf_hi(c0.x), acc[1]);
        acc[2] = fmaf(w0, bf_lo(c0.y), acc[2]);
        acc[3] = fmaf(w0, bf_hi(c0.y), acc[3]);
        acc[4] = fmaf(w0, bf_lo(c0.z), acc[4]);
        acc[5] = fmaf(w0, bf_hi(c0.z), acc[5]);
        acc[6] = fmaf(w0, bf_lo(c0.w), acc[6]);
        acc[7] = fmaf(w0, bf_hi(c0.w), acc[7]);
        acc[0] = fmaf(w1, bf_lo(c1.x), acc[0]);
        acc[1] = fmaf(w1, bf_hi(c1.x), acc[1]);
        acc[2] = fmaf(w1, bf_lo(c1.y), acc[2]);
        acc[3] = fmaf(w1, bf_hi(c1.y), acc[3]);
        acc[4] = fmaf(w1, bf_lo(c1.z), acc[4]);
        acc[5] = fmaf(w1, bf_hi(c1.z), acc[5]);
        acc[6] = fmaf(w1, bf_lo(c1.w), acc[6]);
        acc[7] = fmaf(w1, bf_hi(c1.w), acc[7]);
        c0 = n0; c1 = n1;
    }

    // Fold the 8 pixel subgroups (lane bits 3..5) within each wave.
    #pragma unroll
    for (int e = 0; e < 8; ++e) {
        acc[e] += __shfl_xor(acc[e], 8);
        acc[e] += __shfl_xor(acc[e], 16);
        acc[e] += __shfl_xor(acc[e], 32);
    }

    // Cross-wave partial reduce: wave 1 -> LDS, wave 0 adds + stores.
    __shared__ float part[64];
    if (wid == 1 && lane < 8) {
        #pragma unroll
        for (int e = 0; e < 8; ++e) part[lane * 8 + e] = acc[e];
    }
    __syncthreads();
    if (wid == 0 && lane < 8) {
        // mean over 49 bins of integ/bin_area == acc / ((x2-x1)(y2-y1))
        const float prod  = (x2 - x1) * (y2 - y1);
        const float scale = (prod > 0.0f) ? (1.0f / fmaxf(prod, 49e-12f)) : 0.0f;
        const float* pp = part + lane * 8;
        float* op = out + (size_t)r * C + lane * 8;
        float4 lo = make_float4((acc[0] + pp[0]) * scale, (acc[1] + pp[1]) * scale,
                                (acc[2] + pp[2]) * scale, (acc[3] + pp[3]) * scale);
        float4 hi = make_float4((acc[4] + pp[4]) * scale, (acc[5] + pp[5]) * scale,
                                (acc[6] + pp[6]) * scale, (acc[7] + pp[7]) * scale);
        *reinterpret_cast<float4*>(op)     = lo;
        *reinterpret_cast<float4*>(op + 4) = hi;
    }
}

// ---------------------------------------------------------------------------
// Fallback (round-1 kernel): used only if ws_size is too small.
// ---------------------------------------------------------------------------
__global__ __launch_bounds__(64) void prroi_fallback(
    const float* __restrict__ feature, const float* __restrict__ rois,
    float* __restrict__ out)
{
    const int r  = blockIdx.x;
    const int bo = r / N;
    const int n  = r - bo * N;
    const float* rp = rois + ((size_t)n * B + bo) * 5;
    const float x1 = rp[1], y1 = rp[2], x2 = rp[3], y2 = rp[4];
    const int b = (int)rp[0];
    int i_lo = max(0, (int)ceilf(y1 - 1.0f));
    int i_hi = min(H - 1, (int)floorf(y2 + 1.0f));
    int j_lo = max(0, (int)ceilf(x1 - 1.0f));
    int j_hi = min(W - 1, (int)floorf(x2 + 1.0f));
    const int ny = i_hi - i_lo + 1;
    const int nx = j_hi - j_lo + 1;
    __shared__ float sWy[16], sWx[16];
    const int t = threadIdx.x;
    if (t < 16) {
        int i = i_lo + t;
        sWy[t] = (t < ny) ? (tent_int(y2 - (float)i) - tent_int(y1 - (float)i)) : 0.0f;
    } else if (t < 32) {
        int tt = t - 16, j = j_lo + tt;
        sWx[tt] = (tt < nx) ? (tent_int(x2 - (float)j) - tent_int(x1 - (float)j)) : 0.0f;
    }
    __syncthreads();
    const float* fb = feature + ((size_t)b * C + t) * HW;
    float acc = 0.0f;
    for (int ii = 0; ii < ny; ++ii) {
        const float* row = fb + (size_t)(i_lo + ii) * W + j_lo;
        float rowsum = 0.0f;
        for (int jj = 0; jj < nx; ++jj) rowsum = fmaf(sWx[jj], row[jj], rowsum);
        acc = fmaf(sWy[ii], rowsum, acc);
    }
    const float bw = (x2 - x1) * (1.0f / 7.0f), bh = (y2 - y1) * (1.0f / 7.0f);
    const float area = fmaxf(bw * bh, 0.0f);
    out[(size_t)r * C + t] = (area > 0.0f) ? (acc / (49.0f * fmaxf(area, 1e-12f))) : 0.0f;
}

extern "C" void kernel_launch(void* const* d_in, const int* in_sizes, int n_in,
                              void* d_out, int out_size, void* d_ws, size_t ws_size,
                              hipStream_t stream) {
    const float* feature = (const float*)d_in[0];
    const float* rois    = (const float*)d_in[1];
    float* out           = (float*)d_out;

    const size_t need = (size_t)B * HW * C * sizeof(unsigned short);  // 4 MB
    if (ws_size >= need) {
        unsigned short* ft = (unsigned short*)d_ws;
        transpose_kernel<<<1024, 256, 0, stream>>>(feature, ft);
        prroi_main2<<<R, 128, 0, stream>>>(ft, rois, out);
    } else {
        prroi_fallback<<<R, 64, 0, stream>>>(feature, rois, out);
    }
}